// Round 2
// baseline (287.667 us; speedup 1.0000x reference)
//
#include <hip/hip_runtime.h>
#include <stdint.h>

#define NN    100000
#define FIN   128
#define HIDN  64
#define NCLS  40
#define NE    1600000
#define NBUCK ((NN + 255) / 256)      // 391 buckets of 256 nodes
#define EPB   4096                    // edges per partition block
#define NEB   ((NE + EPB - 1) / EPB)  // 391 partition blocks

typedef unsigned int uint32;

static __device__ __forceinline__ unsigned short f2bf(float f) {
  uint32 u = __float_as_uint(f);
  u = (u + 0x7fffu + ((u >> 16) & 1u)) >> 16;   // RNE
  return (unsigned short)u;
}
static __device__ __forceinline__ uint32 pack2(float lo, float hi) {
  return (uint32)f2bf(lo) | ((uint32)f2bf(hi) << 16);
}
static __device__ __forceinline__ float bf_lo(uint32 v) {
  return __uint_as_float(v << 16);
}
static __device__ __forceinline__ float bf_hi(uint32 v) {
  return __uint_as_float(v & 0xFFFF0000u);
}

// ---- edge dtype probe: int64 (odd u32 words all zero) vs int32 ----
__global__ __launch_bounds__(64) void probe_kernel(const unsigned int* __restrict__ raw,
                                                   int* __restrict__ flag) {
  if (threadIdx.x == 0) {
    int is64 = 1;
    for (int i = 0; i < 64; ++i)
      if (raw[2 * i + 1] != 0u) { is64 = 0; break; }
    *flag = is64;
  }
}

// ---- passA: per-block bucket histogram -> mat[blk][bucket] ----
__global__ __launch_bounds__(256) void passA_kernel(const void* __restrict__ eptr,
                                                    const int* __restrict__ flag,
                                                    int* __restrict__ mat) {
  __shared__ int cnt[NBUCK];
  int tid = threadIdx.x;
  for (int i = tid; i < NBUCK; i += 256) cnt[i] = 0;
  __syncthreads();
  int is64 = *flag;
  int base = blockIdx.x * EPB;
#pragma unroll
  for (int k = 0; k < EPB / 256; ++k) {
    int e = base + k * 256 + tid;
    if (e < NE) {
      int d = is64 ? (int)((const long long*)eptr)[e + NE]
                   : ((const int*)eptr)[e + NE];
      atomicAdd(&cnt[d >> 8], 1);
    }
  }
  __syncthreads();
  for (int i = tid; i < NBUCK; i += 256)
    mat[blockIdx.x * NBUCK + i] = cnt[i];
}

// ---- passB1: per-bucket exclusive scan over blocks; emit bucket totals ----
__global__ __launch_bounds__(512) void passB1_kernel(int* __restrict__ mat,
                                                     int* __restrict__ tot) {
  __shared__ int s[512];
  int b = blockIdx.x;         // bucket
  int t = threadIdx.x;        // block index
  int v = (t < NEB) ? mat[t * NBUCK + b] : 0;
  s[t] = v;
  __syncthreads();
#pragma unroll
  for (int d = 1; d < 512; d <<= 1) {
    int u = (t >= d) ? s[t - d] : 0;
    __syncthreads();
    s[t] += u;
    __syncthreads();
  }
  if (t < NEB) mat[t * NBUCK + b] = s[t] - v;  // exclusive prefix within bucket
  if (t == 511) tot[b] = s[511];
}

// ---- passB2: exclusive scan of bucket totals -> bbase ----
__global__ __launch_bounds__(512) void passB2_kernel(const int* __restrict__ tot,
                                                     int* __restrict__ bbase) {
  __shared__ int s[512];
  int i = threadIdx.x;
  int v = (i < NBUCK) ? tot[i] : 0;
  s[i] = v;
  __syncthreads();
#pragma unroll
  for (int d = 1; d < 512; d <<= 1) {
    int u = (i >= d) ? s[i - d] : 0;
    __syncthreads();
    s[i] += u;
    __syncthreads();
  }
  if (i < NBUCK) bbase[i] = s[i] - v;
  if (i == 511) bbase[NBUCK] = s[511];
}

// ---- passC: place edges into compact bucket-sorted bbuf (LDS cursors) ----
__global__ __launch_bounds__(256) void passC_kernel(const void* __restrict__ eptr,
                                                    const int* __restrict__ flag,
                                                    const int* __restrict__ mat,
                                                    const int* __restrict__ bbase,
                                                    uint32* __restrict__ bbuf) {
  __shared__ int cur[NBUCK];
  int tid = threadIdx.x;
  for (int i = tid; i < NBUCK; i += 256)
    cur[i] = bbase[i] + mat[blockIdx.x * NBUCK + i];
  __syncthreads();
  int is64 = *flag;
  int base = blockIdx.x * EPB;
#pragma unroll
  for (int k = 0; k < EPB / 256; ++k) {
    int e = base + k * 256 + tid;
    if (e < NE) {
      int s, d;
      if (is64) {
        const long long* p = (const long long*)eptr;
        s = (int)p[e]; d = (int)p[e + NE];
      } else {
        const int* p = (const int*)eptr;
        s = p[e]; d = p[e + NE];
      }
      int slot = atomicAdd(&cur[d >> 8], 1);
      bbuf[slot] = (uint32)s | ((uint32)(d & 255) << 17);
    }
  }
}

// ---- build: per-bucket CSR (LDS hist + scan + rank placement) ----
__global__ __launch_bounds__(256) void build_kernel(const int* __restrict__ bbase,
                                                    const uint32* __restrict__ bbuf,
                                                    int* __restrict__ off,
                                                    float* __restrict__ dinv,
                                                    int* __restrict__ s_src) {
  __shared__ int hist[256];
  __shared__ int lofs[256];
  __shared__ int rank[256];
  int b = blockIdx.x, tid = threadIdx.x;
  int base = bbase[b];
  int count = bbase[b + 1] - base;
  const uint32* p = bbuf + base;
  hist[tid] = 0;
  __syncthreads();
  for (int i = tid; i < count; i += 256) atomicAdd(&hist[p[i] >> 17], 1);
  __syncthreads();
  int deg = hist[tid];
  lofs[tid] = deg;
  __syncthreads();
#pragma unroll
  for (int dd = 1; dd < 256; dd <<= 1) {
    int t = (tid >= dd) ? lofs[tid - dd] : 0;
    __syncthreads();
    lofs[tid] += t;
    __syncthreads();
  }
  int excl = lofs[tid] - deg;
  __syncthreads();
  lofs[tid] = excl;
  rank[tid] = 0;
  int n = b * 256 + tid;
  if (n < NN) {
    off[n] = base + excl;
    dinv[n] = rsqrtf((float)deg + 1.0f);
  }
  if (b == 0 && tid == 0) off[NN] = NE;
  __syncthreads();
  for (int i = tid; i < count; i += 256) {
    uint32 v = p[i];
    int dl = (int)(v >> 17);
    int s = (int)(v & 0x1FFFFu);
    int r = atomicAdd(&rank[dl], 1);
    s_src[base + lofs[dl] + r] = s;
  }
}

// ---- GEMM1: hs[N,64](bf16) = (x[N,128] @ W1[128,64]) * dinv[row] ----
// R11: explicit double-buffered x prefetch. R10 showed occupancy was not
// the limit (13->20% occ, dur 55->50us, VALUBusy 35%): waves stall on the
// per-iteration x load the compiler doesn't pipeline across iterations.
// Load chunk k+1 into the alternate buffer BEFORE computing chunk k so
// every global load has ~256 FMA-cycles of cover in program order.
__global__ __launch_bounds__(256) void gemm1_kernel(const float* __restrict__ x,
                                                    const float* __restrict__ W,
                                                    const float* __restrict__ dinv,
                                                    uint32* __restrict__ hs) {
  __shared__ float sW[FIN * HIDN];  // 32 KB
  int tid = threadIdx.x;
  {
    const float4* W4 = (const float4*)W;
    float4* sW4 = (float4*)sW;
#pragma unroll
    for (int i = 0; i < 8; ++i) sW4[i * 256 + tid] = W4[i * 256 + tid];
  }
  __syncthreads();
  int cg = tid & 7;            // 8 col groups of 8
  int rp = tid >> 3;           // 32 row groups of 4 rows
  int r0 = blockIdx.x * 128 + rp * 4;
  int c0 = cg * 8;
  bool v[4];
#pragma unroll
  for (int r = 0; r < 4; ++r) v[r] = (r0 + r) < NN;
  float4 acc[4][2];            // [row][col quad]
#pragma unroll
  for (int r = 0; r < 4; ++r)
#pragma unroll
    for (int j = 0; j < 2; ++j) acc[r][j] = make_float4(0.f, 0.f, 0.f, 0.f);
  const float4* x4 = (const float4*)x;
  const float4 z4 = make_float4(0.f, 0.f, 0.f, 0.f);

  float4 xa[4], xb[4];
#pragma unroll
  for (int r = 0; r < 4; ++r)
    xa[r] = v[r] ? x4[(size_t)(r0 + r) * 32 + 0] : z4;

#define GEMM1_STEP(XR, K0)                                               \
  do {                                                                   \
    _Pragma("unroll")                                                    \
    for (int kk = 0; kk < 4; ++kk) {                                     \
      _Pragma("unroll")                                                  \
      for (int j = 0; j < 2; ++j) {                                      \
        float4 wv = *(const float4*)&sW[((K0) + kk) * HIDN + c0 + 4 * j];\
        _Pragma("unroll")                                                \
        for (int r = 0; r < 4; ++r) {                                    \
          float xv = (&XR[r].x)[kk];                                     \
          acc[r][j].x = fmaf(xv, wv.x, acc[r][j].x);                     \
          acc[r][j].y = fmaf(xv, wv.y, acc[r][j].y);                     \
          acc[r][j].z = fmaf(xv, wv.z, acc[r][j].z);                     \
          acc[r][j].w = fmaf(xv, wv.w, acc[r][j].w);                     \
        }                                                                \
      }                                                                  \
    }                                                                    \
  } while (0)

#pragma unroll 1
  for (int kc = 0; kc < 32; kc += 2) {
    // prefetch chunk kc+1 while computing chunk kc
#pragma unroll
    for (int r = 0; r < 4; ++r)
      xb[r] = v[r] ? x4[(size_t)(r0 + r) * 32 + kc + 1] : z4;
    GEMM1_STEP(xa, kc * 4);
    // prefetch chunk kc+2 while computing chunk kc+1
    int nidx = (kc + 2 < 32) ? kc + 2 : 31;   // harmless reload on last iter
#pragma unroll
    for (int r = 0; r < 4; ++r)
      xa[r] = v[r] ? x4[(size_t)(r0 + r) * 32 + nidx] : z4;
    GEMM1_STEP(xb, kc * 4 + 4);
  }
#undef GEMM1_STEP

#pragma unroll
  for (int r = 0; r < 4; ++r) {
    if (!v[r]) continue;
    float di = dinv[r0 + r];
    uint4 q;
    q.x = pack2(acc[r][0].x * di, acc[r][0].y * di);
    q.y = pack2(acc[r][0].z * di, acc[r][0].w * di);
    q.z = pack2(acc[r][1].x * di, acc[r][1].y * di);
    q.w = pack2(acc[r][1].z * di, acc[r][1].w * di);
    uint4* hp = (uint4*)&hs[(size_t)(r0 + r) * 32 + cg * 4];
    hp[0] = q;
  }
}

// ---- agg1: 8 lanes/edge (uint4=16B), 8 edge slots/wave, unroll x2 ->
// 16 gathers in flight. g[n] = bf16(dinv_n*relu(dinv_n*(hs[n]+sum)+b1)) ----
__global__ __launch_bounds__(256) void agg1_kernel(const int* __restrict__ off,
                                                   const int* __restrict__ s_src,
                                                   const uint4* __restrict__ hs4,
                                                   const float* __restrict__ dinv,
                                                   const float* __restrict__ b1,
                                                   uint4* __restrict__ g) {
  int n = blockIdx.x * 4 + (threadIdx.x >> 6);     // NN = 25000*4 exactly
  int lane = threadIdx.x & 63;
  int q = lane >> 3;           // edge slot 0..7
  int hc = lane & 7;           // 8-col chunk (cols 8hc..8hc+7)
  int j0 = off[n], j1 = off[n + 1];
  float a[8];
#pragma unroll
  for (int i = 0; i < 8; ++i) a[i] = 0.f;
  if (q == 0) {
    uint4 v = hs4[(size_t)n * 8 + hc];
    a[0] = bf_lo(v.x); a[1] = bf_hi(v.x); a[2] = bf_lo(v.y); a[3] = bf_hi(v.y);
    a[4] = bf_lo(v.z); a[5] = bf_hi(v.z); a[6] = bf_lo(v.w); a[7] = bf_hi(v.w);
  }
  int j = j0 + q;
  for (; j + 8 < j1; j += 16) {
    int sa = s_src[j], sb = s_src[j + 8];
    uint4 va = hs4[(size_t)sa * 8 + hc];
    uint4 vb = hs4[(size_t)sb * 8 + hc];
    a[0] += bf_lo(va.x); a[1] += bf_hi(va.x); a[2] += bf_lo(va.y); a[3] += bf_hi(va.y);
    a[4] += bf_lo(va.z); a[5] += bf_hi(va.z); a[6] += bf_lo(va.w); a[7] += bf_hi(va.w);
    a[0] += bf_lo(vb.x); a[1] += bf_hi(vb.x); a[2] += bf_lo(vb.y); a[3] += bf_hi(vb.y);
    a[4] += bf_lo(vb.z); a[5] += bf_hi(vb.z); a[6] += bf_lo(vb.w); a[7] += bf_hi(vb.w);
  }
  if (j < j1) {
    int sa = s_src[j];
    uint4 va = hs4[(size_t)sa * 8 + hc];
    a[0] += bf_lo(va.x); a[1] += bf_hi(va.x); a[2] += bf_lo(va.y); a[3] += bf_hi(va.y);
    a[4] += bf_lo(va.z); a[5] += bf_hi(va.z); a[6] += bf_lo(va.w); a[7] += bf_hi(va.w);
  }
#pragma unroll
  for (int i = 0; i < 8; ++i) {
    a[i] += __shfl_xor(a[i], 8, 64);
    a[i] += __shfl_xor(a[i], 16, 64);
    a[i] += __shfl_xor(a[i], 32, 64);
  }
  if (q == 0) {
    float di = dinv[n];
    float4 b0 = *(const float4*)&b1[hc * 8];
    float4 b4 = *(const float4*)&b1[hc * 8 + 4];
    float r0 = di * fmaxf(a[0] * di + b0.x, 0.f);
    float r1 = di * fmaxf(a[1] * di + b0.y, 0.f);
    float r2 = di * fmaxf(a[2] * di + b0.z, 0.f);
    float r3 = di * fmaxf(a[3] * di + b0.w, 0.f);
    float r4 = di * fmaxf(a[4] * di + b4.x, 0.f);
    float r5 = di * fmaxf(a[5] * di + b4.y, 0.f);
    float r6 = di * fmaxf(a[6] * di + b4.z, 0.f);
    float r7 = di * fmaxf(a[7] * di + b4.w, 0.f);
    uint4 o;
    o.x = pack2(r0, r1); o.y = pack2(r2, r3);
    o.z = pack2(r4, r5); o.w = pack2(r6, r7);
    g[(size_t)n * 8 + hc] = o;    // 8 lanes x 16 B = 128 B contiguous
  }
}

// ---- agg2: same gather shape on g; t[n] = dinv_n*(g[n]+sum_j g[s_j]) (fp32) ----
__global__ __launch_bounds__(256) void agg2_kernel(const int* __restrict__ off,
                                                   const int* __restrict__ s_src,
                                                   const uint4* __restrict__ g,
                                                   const float* __restrict__ dinv,
                                                   float* __restrict__ t) {
  int n = blockIdx.x * 4 + (threadIdx.x >> 6);
  int lane = threadIdx.x & 63;
  int q = lane >> 3;
  int hc = lane & 7;
  int j0 = off[n], j1 = off[n + 1];
  float a[8];
#pragma unroll
  for (int i = 0; i < 8; ++i) a[i] = 0.f;
  if (q == 0) {
    uint4 v = g[(size_t)n * 8 + hc];
    a[0] = bf_lo(v.x); a[1] = bf_hi(v.x); a[2] = bf_lo(v.y); a[3] = bf_hi(v.y);
    a[4] = bf_lo(v.z); a[5] = bf_hi(v.z); a[6] = bf_lo(v.w); a[7] = bf_hi(v.w);
  }
  int j = j0 + q;
  for (; j + 8 < j1; j += 16) {
    int sa = s_src[j], sb = s_src[j + 8];
    uint4 va = g[(size_t)sa * 8 + hc];
    uint4 vb = g[(size_t)sb * 8 + hc];
    a[0] += bf_lo(va.x); a[1] += bf_hi(va.x); a[2] += bf_lo(va.y); a[3] += bf_hi(va.y);
    a[4] += bf_lo(va.z); a[5] += bf_hi(va.z); a[6] += bf_lo(va.w); a[7] += bf_hi(va.w);
    a[0] += bf_lo(vb.x); a[1] += bf_hi(vb.x); a[2] += bf_lo(vb.y); a[3] += bf_hi(vb.y);
    a[4] += bf_lo(vb.z); a[5] += bf_hi(vb.z); a[6] += bf_lo(vb.w); a[7] += bf_hi(vb.w);
  }
  if (j < j1) {
    int sa = s_src[j];
    uint4 va = g[(size_t)sa * 8 + hc];
    a[0] += bf_lo(va.x); a[1] += bf_hi(va.x); a[2] += bf_lo(va.y); a[3] += bf_hi(va.y);
    a[4] += bf_lo(va.z); a[5] += bf_hi(va.z); a[6] += bf_lo(va.w); a[7] += bf_hi(va.w);
  }
#pragma unroll
  for (int i = 0; i < 8; ++i) {
    a[i] += __shfl_xor(a[i], 8, 64);
    a[i] += __shfl_xor(a[i], 16, 64);
    a[i] += __shfl_xor(a[i], 32, 64);
  }
  if (q == 0) {
    float di = dinv[n];
    float* tp = &t[(size_t)n * HIDN + hc * 8];
    *(float4*)tp = make_float4(a[0] * di, a[1] * di, a[2] * di, a[3] * di);
    *(float4*)(tp + 4) = make_float4(a[4] * di, a[5] * di, a[6] * di, a[7] * di);
  }
}

// ---- mv: out[N,40] = t[N,64] @ W2[64,40] + b2 ----
// Low-pressure shape (R9-proven): 256 thr = 128 rows x 2 col-groups of 20.
__global__ __launch_bounds__(256) void mv_kernel(const float* __restrict__ t,
                                                 const float* __restrict__ W2,
                                                 const float* __restrict__ b2,
                                                 float* __restrict__ out) {
  __shared__ float sW[HIDN * NCLS];  // 10 KB
  int tid = threadIdx.x;
  for (int i = tid; i < (HIDN * NCLS) / 4; i += 256)
    ((float4*)sW)[i] = ((const float4*)W2)[i];
  __syncthreads();
  int cg = tid & 1;
  int r = blockIdx.x * 128 + (tid >> 1);
  if (r >= NN) return;
  int c0 = cg * 20;
  float acc[20];
#pragma unroll
  for (int j = 0; j < 20; ++j) acc[j] = b2[c0 + j];
  const float4* t4 = (const float4*)(t + (size_t)r * HIDN);
#pragma unroll 4
  for (int k4 = 0; k4 < 16; ++k4) {
    float4 tv = t4[k4];
#pragma unroll
    for (int kk = 0; kk < 4; ++kk) {
      float xv = (&tv.x)[kk];
      const float* wr = &sW[(k4 * 4 + kk) * NCLS + c0];
#pragma unroll
      for (int j = 0; j < 5; ++j) {
        float4 wv = *(const float4*)&wr[j * 4];
        acc[j * 4 + 0] = fmaf(xv, wv.x, acc[j * 4 + 0]);
        acc[j * 4 + 1] = fmaf(xv, wv.y, acc[j * 4 + 1]);
        acc[j * 4 + 2] = fmaf(xv, wv.z, acc[j * 4 + 2]);
        acc[j * 4 + 3] = fmaf(xv, wv.w, acc[j * 4 + 3]);
      }
    }
  }
  float4* op = (float4*)&out[(size_t)r * NCLS + c0];
#pragma unroll
  for (int j = 0; j < 5; ++j)
    op[j] = make_float4(acc[j * 4 + 0], acc[j * 4 + 1],
                        acc[j * 4 + 2], acc[j * 4 + 3]);
}

extern "C" void kernel_launch(void* const* d_in, const int* in_sizes, int n_in,
                              void* d_out, int out_size, void* d_ws, size_t ws_size,
                              hipStream_t stream) {
  const float* x  = (const float*)d_in[0];
  const void*  ei = d_in[1];
  const float* W1 = (const float*)d_in[2];
  const float* b1 = (const float*)d_in[3];
  const float* W2 = (const float*)d_in[4];
  const float* b2 = (const float*)d_in[5];
  float* out = (float*)d_out;

  char* w = (char*)d_ws;
  size_t off_b = 0;
  auto carve = [&](size_t bytes) -> void* {
    void* p = w + off_b;
    off_b = (off_b + bytes + 255) & ~(size_t)255;
    return p;
  };
  int*    mat   = (int*)   carve((size_t)NEB * NBUCK * 4);   // 611 KB
  int*    tot   = (int*)   carve((size_t)NBUCK * 4);
  int*    bbase = (int*)   carve((size_t)(NBUCK + 1) * 4);
  int*    offs  = (int*)   carve((size_t)(NN + 1) * 4);
  float*  dinv  = (float*) carve((size_t)NN * 4);
  int*    flag  = (int*)   carve(256);
  int*    s_src = (int*)   carve((size_t)NE * 4);
  uint32* hs    = (uint32*)carve((size_t)NN * 32 * 4);       // bf16 h, 12.8 MB
  uint4*  g     = (uint4*) carve((size_t)NN * 8 * 16);       // bf16 g, 12.8 MB
  float*  t     = (float*) carve((size_t)NN * HIDN * 4);     // fp32, 25.6 MB
  uint32* bbuf  = (uint32*)carve((size_t)NE * 4);            // 6.4 MB

  probe_kernel<<<1, 64, 0, stream>>>((const unsigned int*)ei, flag);
  passA_kernel<<<NEB, 256, 0, stream>>>(ei, flag, mat);
  passB1_kernel<<<NBUCK, 512, 0, stream>>>(mat, tot);
  passB2_kernel<<<1, 512, 0, stream>>>(tot, bbase);
  passC_kernel<<<NEB, 256, 0, stream>>>(ei, flag, mat, bbase, bbuf);
  build_kernel<<<NBUCK, 256, 0, stream>>>(bbase, bbuf, offs, dinv, s_src);
  gemm1_kernel<<<(NN + 127) / 128, 256, 0, stream>>>(x, W1, dinv, hs);
  agg1_kernel<<<NN / 4, 256, 0, stream>>>(offs, s_src, (const uint4*)hs, dinv, b1, g);
  agg2_kernel<<<NN / 4, 256, 0, stream>>>(offs, s_src, g, dinv, t);
  mv_kernel<<<(NN + 127) / 128, 256, 0, stream>>>(t, W2, b2, out);
}

// Round 3
// 262.031 us; speedup vs baseline: 1.0978x; 1.0978x over previous
//
#include <hip/hip_runtime.h>
#include <stdint.h>

#define NN    100000
#define FIN   128
#define HIDN  64
#define NCLS  40
#define NE    1600000
#define NBUCK ((NN + 255) / 256)      // 391 buckets of 256 nodes
#define EPB   4096                    // edges per partition block
#define NEB   ((NE + EPB - 1) / EPB)  // 391 partition blocks

typedef unsigned int uint32;
typedef __attribute__((ext_vector_type(8))) short short8v;
typedef __attribute__((ext_vector_type(4))) float f32x4;

static __device__ __forceinline__ unsigned short f2bf(float f) {
  uint32 u = __float_as_uint(f);
  u = (u + 0x7fffu + ((u >> 16) & 1u)) >> 16;   // RNE
  return (unsigned short)u;
}
static __device__ __forceinline__ uint32 pack2(float lo, float hi) {
  return (uint32)f2bf(lo) | ((uint32)f2bf(hi) << 16);
}
static __device__ __forceinline__ float bf_lo(uint32 v) {
  return __uint_as_float(v << 16);
}
static __device__ __forceinline__ float bf_hi(uint32 v) {
  return __uint_as_float(v & 0xFFFF0000u);
}
static __device__ __forceinline__ f32x4 mfma_bf16(uint4 a, uint4 b, f32x4 c) {
  short8v av = __builtin_bit_cast(short8v, a);
  short8v bv = __builtin_bit_cast(short8v, b);
  return __builtin_amdgcn_mfma_f32_16x16x32_bf16(av, bv, c, 0, 0, 0);
}

// permuted hs/g/t column map: float index z in [0,64) -> true column.
// Produced by gemm1's MFMA epilogue word layout; consumed by b1/W2 remaps.
static __device__ __forceinline__ int perm_col(int z) {
  return 4 * (z >> 3) + ((z & 7) >> 1) + 16 * (z & 1) + ((z >= 32) ? 16 : 0);
}

// ---- edge dtype probe: int64 (odd u32 words all zero) vs int32 ----
__global__ __launch_bounds__(64) void probe_kernel(const unsigned int* __restrict__ raw,
                                                   int* __restrict__ flag) {
  if (threadIdx.x == 0) {
    int is64 = 1;
    for (int i = 0; i < 64; ++i)
      if (raw[2 * i + 1] != 0u) { is64 = 0; break; }
    *flag = is64;
  }
}

// ---- wfrag: W1[128][64] fp32 -> MFMA B-frag order, split hi/lo bf16 ----
// frag idx = ((t*4 + kr)*4 + nr)*64 + lane ; lane holds B[k][n] for
// n = nr*16 + (lane&15), k = kr*32 + (lane>>4)*8 + i, i=0..7 (bf16 pairs).
__global__ __launch_bounds__(64) void wfrag_kernel(const float* __restrict__ W,
                                                   uint4* __restrict__ wfrag) {
  int idx = blockIdx.x * 64 + threadIdx.x;   // 0..2047 over grid 32x64
  int lane = idx & 63;
  int nr = (idx >> 6) & 3;
  int kr = (idx >> 8) & 3;
  int t  = idx >> 10;                        // 0 = hi, 1 = lo
  int n  = nr * 16 + (lane & 15);
  int k0 = kr * 32 + (lane >> 4) * 8;
  uint32 w[4];
#pragma unroll
  for (int j = 0; j < 4; ++j) {
    float a = W[(k0 + 2 * j) * HIDN + n];
    float b = W[(k0 + 2 * j + 1) * HIDN + n];
    uint32 ha = f2bf(a), hb = f2bf(b);
    if (t == 0) {
      w[j] = ha | (hb << 16);
    } else {
      float ra = a - __uint_as_float(ha << 16);
      float rb = b - __uint_as_float(hb << 16);
      w[j] = (uint32)f2bf(ra) | ((uint32)f2bf(rb) << 16);
    }
  }
  wfrag[idx] = make_uint4(w[0], w[1], w[2], w[3]);
}

// ---- passA: per-block bucket histogram -> mat[blk][bucket] ----
__global__ __launch_bounds__(256) void passA_kernel(const void* __restrict__ eptr,
                                                    const int* __restrict__ flag,
                                                    int* __restrict__ mat) {
  __shared__ int cnt[NBUCK];
  int tid = threadIdx.x;
  for (int i = tid; i < NBUCK; i += 256) cnt[i] = 0;
  __syncthreads();
  int is64 = *flag;
  int base = blockIdx.x * EPB;
#pragma unroll
  for (int k = 0; k < EPB / 256; ++k) {
    int e = base + k * 256 + tid;
    if (e < NE) {
      int d = is64 ? (int)((const long long*)eptr)[e + NE]
                   : ((const int*)eptr)[e + NE];
      atomicAdd(&cnt[d >> 8], 1);
    }
  }
  __syncthreads();
  for (int i = tid; i < NBUCK; i += 256)
    mat[blockIdx.x * NBUCK + i] = cnt[i];
}

// ---- passB1: per-bucket exclusive scan over blocks; emit bucket totals ----
__global__ __launch_bounds__(512) void passB1_kernel(int* __restrict__ mat,
                                                     int* __restrict__ tot) {
  __shared__ int s[512];
  int b = blockIdx.x;         // bucket
  int t = threadIdx.x;        // block index
  int v = (t < NEB) ? mat[t * NBUCK + b] : 0;
  s[t] = v;
  __syncthreads();
#pragma unroll
  for (int d = 1; d < 512; d <<= 1) {
    int u = (t >= d) ? s[t - d] : 0;
    __syncthreads();
    s[t] += u;
    __syncthreads();
  }
  if (t < NEB) mat[t * NBUCK + b] = s[t] - v;  // exclusive prefix within bucket
  if (t == 511) tot[b] = s[511];
}

// ---- passB2: exclusive scan of bucket totals -> bbase ----
__global__ __launch_bounds__(512) void passB2_kernel(const int* __restrict__ tot,
                                                     int* __restrict__ bbase) {
  __shared__ int s[512];
  int i = threadIdx.x;
  int v = (i < NBUCK) ? tot[i] : 0;
  s[i] = v;
  __syncthreads();
#pragma unroll
  for (int d = 1; d < 512; d <<= 1) {
    int u = (i >= d) ? s[i - d] : 0;
    __syncthreads();
    s[i] += u;
    __syncthreads();
  }
  if (i < NBUCK) bbase[i] = s[i] - v;
  if (i == 511) bbase[NBUCK] = s[511];
}

// ---- passC: place edges into compact bucket-sorted bbuf (LDS cursors) ----
__global__ __launch_bounds__(256) void passC_kernel(const void* __restrict__ eptr,
                                                    const int* __restrict__ flag,
                                                    const int* __restrict__ mat,
                                                    const int* __restrict__ bbase,
                                                    uint32* __restrict__ bbuf) {
  __shared__ int cur[NBUCK];
  int tid = threadIdx.x;
  for (int i = tid; i < NBUCK; i += 256)
    cur[i] = bbase[i] + mat[blockIdx.x * NBUCK + i];
  __syncthreads();
  int is64 = *flag;
  int base = blockIdx.x * EPB;
#pragma unroll
  for (int k = 0; k < EPB / 256; ++k) {
    int e = base + k * 256 + tid;
    if (e < NE) {
      int s, d;
      if (is64) {
        const long long* p = (const long long*)eptr;
        s = (int)p[e]; d = (int)p[e + NE];
      } else {
        const int* p = (const int*)eptr;
        s = p[e]; d = p[e + NE];
      }
      int slot = atomicAdd(&cur[d >> 8], 1);
      bbuf[slot] = (uint32)s | ((uint32)(d & 255) << 17);
    }
  }
}

// ---- build: per-bucket CSR (LDS hist + scan + rank placement) ----
__global__ __launch_bounds__(256) void build_kernel(const int* __restrict__ bbase,
                                                    const uint32* __restrict__ bbuf,
                                                    int* __restrict__ off,
                                                    float* __restrict__ dinv,
                                                    int* __restrict__ s_src) {
  __shared__ int hist[256];
  __shared__ int lofs[256];
  __shared__ int rank[256];
  int b = blockIdx.x, tid = threadIdx.x;
  int base = bbase[b];
  int count = bbase[b + 1] - base;
  const uint32* p = bbuf + base;
  hist[tid] = 0;
  __syncthreads();
  for (int i = tid; i < count; i += 256) atomicAdd(&hist[p[i] >> 17], 1);
  __syncthreads();
  int deg = hist[tid];
  lofs[tid] = deg;
  __syncthreads();
#pragma unroll
  for (int dd = 1; dd < 256; dd <<= 1) {
    int t = (tid >= dd) ? lofs[tid - dd] : 0;
    __syncthreads();
    lofs[tid] += t;
    __syncthreads();
  }
  int excl = lofs[tid] - deg;
  __syncthreads();
  lofs[tid] = excl;
  rank[tid] = 0;
  int n = b * 256 + tid;
  if (n < NN) {
    off[n] = base + excl;
    dinv[n] = rsqrtf((float)deg + 1.0f);
  }
  if (b == 0 && tid == 0) off[NN] = NE;
  __syncthreads();
  for (int i = tid; i < count; i += 256) {
    uint32 v = p[i];
    int dl = (int)(v >> 17);
    int s = (int)(v & 0x1FFFFu);
    int r = atomicAdd(&rank[dl], 1);
    s_src[base + lofs[dl] + r] = s;
  }
}

// ---- GEMM1 (MFMA): hs'[N,64](bf16, perm cols) = (x @ W1) * dinv[row] ----
// R12: mfma_f32_16x16x32_bf16, split-precision (xh*wh + xh*wl + xl*wh ~ fp32).
// Per wave: 32 rows x 64 cols, 2x4 acc frags, K=128 in 4 chunks, 96 MFMAs.
// W frags read from precomputed wfrag (coalesced dwordx4, L2-hot). No LDS.
// hs words: w = 16a + (lane&15) holds cols (16*2a + l15, 16*(2a+1) + l15)
// -> perm_col(z) map; b1 (agg1) and W2 (mv) are remapped to match.
__global__ __launch_bounds__(256) void gemm1_kernel(const float* __restrict__ x,
                                                    const uint4* __restrict__ wfrag,
                                                    const float* __restrict__ dinv,
                                                    uint32* __restrict__ hs) {
  int wid = blockIdx.x * 4 + (threadIdx.x >> 6);
  if (wid >= NN / 32) return;                 // 3125 waves exactly, no LDS
  int lane = threadIdx.x & 63;
  int l15 = lane & 15, lg = lane >> 4;
  int r0 = wid * 32;
  f32x4 acc[2][4];
#pragma unroll
  for (int mr = 0; mr < 2; ++mr)
#pragma unroll
    for (int nr = 0; nr < 4; ++nr) acc[mr][nr] = (f32x4)0.f;
  const float4* x4 = (const float4*)x;
#pragma unroll
  for (int kr = 0; kr < 4; ++kr) {
    uint4 ah[2], al[2];
#pragma unroll
    for (int mr = 0; mr < 2; ++mr) {
      int m = r0 + mr * 16 + l15;
      int q0 = m * 32 + kr * 8 + lg * 2;      // float4 index of k0 = kr*32+lg*8
      float4 u = x4[q0], v = x4[q0 + 1];
      float xs[8] = {u.x, u.y, u.z, u.w, v.x, v.y, v.z, v.w};
      uint32 hw[4], lw[4];
#pragma unroll
      for (int j = 0; j < 4; ++j) {
        float a0 = xs[2 * j], a1 = xs[2 * j + 1];
        uint32 h0 = f2bf(a0), h1 = f2bf(a1);
        float ra = a0 - __uint_as_float(h0 << 16);
        float rb = a1 - __uint_as_float(h1 << 16);
        hw[j] = h0 | (h1 << 16);
        lw[j] = (uint32)f2bf(ra) | ((uint32)f2bf(rb) << 16);
      }
      ah[mr] = make_uint4(hw[0], hw[1], hw[2], hw[3]);
      al[mr] = make_uint4(lw[0], lw[1], lw[2], lw[3]);
    }
#pragma unroll
    for (int nr = 0; nr < 4; ++nr) {
      uint4 bh = wfrag[(kr * 4 + nr) * 64 + lane];          // hi set (t=0)
      uint4 bl = wfrag[((4 + kr) * 4 + nr) * 64 + lane];    // lo set (t=1)
#pragma unroll
      for (int mr = 0; mr < 2; ++mr) {
        acc[mr][nr] = mfma_bf16(ah[mr], bh, acc[mr][nr]);
        acc[mr][nr] = mfma_bf16(al[mr], bh, acc[mr][nr]);
        acc[mr][nr] = mfma_bf16(ah[mr], bl, acc[mr][nr]);
      }
    }
  }
  // epilogue: C/D frag row = 4*lg + j (within 16-tile), col = nr*16 + l15
#pragma unroll
  for (int mr = 0; mr < 2; ++mr) {
    int rb = r0 + mr * 16 + 4 * lg;
    float4 dv = *(const float4*)&dinv[rb];
#pragma unroll
    for (int a = 0; a < 2; ++a) {
#pragma unroll
      for (int j = 0; j < 4; ++j) {
        float d = (&dv.x)[j];
        uint32 wv = pack2(acc[mr][2 * a][j] * d, acc[mr][2 * a + 1][j] * d);
        hs[(size_t)(rb + j) * 32 + a * 16 + l15] = wv;
      }
    }
  }
}

// ---- agg1: 8 lanes/edge (uint4=16B), 8 edge slots/wave, unroll x2 ->
// 16 gathers in flight. g[n] = bf16(dinv_n*relu(dinv_n*(hs[n]+sum)+b1)) ----
// b1 loaded via perm_col (hs cols are permuted); g inherits the layout.
__global__ __launch_bounds__(256) void agg1_kernel(const int* __restrict__ off,
                                                   const int* __restrict__ s_src,
                                                   const uint4* __restrict__ hs4,
                                                   const float* __restrict__ dinv,
                                                   const float* __restrict__ b1,
                                                   uint4* __restrict__ g) {
  int n = blockIdx.x * 4 + (threadIdx.x >> 6);     // NN = 25000*4 exactly
  int lane = threadIdx.x & 63;
  int q = lane >> 3;           // edge slot 0..7
  int hc = lane & 7;           // 8-col chunk (words 4hc..4hc+3)
  int j0 = off[n], j1 = off[n + 1];
  float a[8];
#pragma unroll
  for (int i = 0; i < 8; ++i) a[i] = 0.f;
  if (q == 0) {
    uint4 v = hs4[(size_t)n * 8 + hc];
    a[0] = bf_lo(v.x); a[1] = bf_hi(v.x); a[2] = bf_lo(v.y); a[3] = bf_hi(v.y);
    a[4] = bf_lo(v.z); a[5] = bf_hi(v.z); a[6] = bf_lo(v.w); a[7] = bf_hi(v.w);
  }
  int j = j0 + q;
  for (; j + 8 < j1; j += 16) {
    int sa = s_src[j], sb = s_src[j + 8];
    uint4 va = hs4[(size_t)sa * 8 + hc];
    uint4 vb = hs4[(size_t)sb * 8 + hc];
    a[0] += bf_lo(va.x); a[1] += bf_hi(va.x); a[2] += bf_lo(va.y); a[3] += bf_hi(va.y);
    a[4] += bf_lo(va.z); a[5] += bf_hi(va.z); a[6] += bf_lo(va.w); a[7] += bf_hi(va.w);
    a[0] += bf_lo(vb.x); a[1] += bf_hi(vb.x); a[2] += bf_lo(vb.y); a[3] += bf_hi(vb.y);
    a[4] += bf_lo(vb.z); a[5] += bf_hi(vb.z); a[6] += bf_lo(vb.w); a[7] += bf_hi(vb.w);
  }
  if (j < j1) {
    int sa = s_src[j];
    uint4 va = hs4[(size_t)sa * 8 + hc];
    a[0] += bf_lo(va.x); a[1] += bf_hi(va.x); a[2] += bf_lo(va.y); a[3] += bf_hi(va.y);
    a[4] += bf_lo(va.z); a[5] += bf_hi(va.z); a[6] += bf_lo(va.w); a[7] += bf_hi(va.w);
  }
#pragma unroll
  for (int i = 0; i < 8; ++i) {
    a[i] += __shfl_xor(a[i], 8, 64);
    a[i] += __shfl_xor(a[i], 16, 64);
    a[i] += __shfl_xor(a[i], 32, 64);
  }
  if (q == 0) {
    float di = dinv[n];
    float bb[8];
#pragma unroll
    for (int i = 0; i < 8; ++i)
      bb[i] = b1[perm_col(hc * 8 + i)];
    float r0 = di * fmaxf(a[0] * di + bb[0], 0.f);
    float r1 = di * fmaxf(a[1] * di + bb[1], 0.f);
    float r2 = di * fmaxf(a[2] * di + bb[2], 0.f);
    float r3 = di * fmaxf(a[3] * di + bb[3], 0.f);
    float r4 = di * fmaxf(a[4] * di + bb[4], 0.f);
    float r5 = di * fmaxf(a[5] * di + bb[5], 0.f);
    float r6 = di * fmaxf(a[6] * di + bb[6], 0.f);
    float r7 = di * fmaxf(a[7] * di + bb[7], 0.f);
    uint4 o;
    o.x = pack2(r0, r1); o.y = pack2(r2, r3);
    o.z = pack2(r4, r5); o.w = pack2(r6, r7);
    g[(size_t)n * 8 + hc] = o;    // 8 lanes x 16 B = 128 B contiguous
  }
}

// ---- agg2: same gather shape on g; t[n] = dinv_n*(g[n]+sum_j g[s_j]) (fp32) ----
// Layout-transparent: t' keeps the permuted column order; mv remaps W2 rows.
__global__ __launch_bounds__(256) void agg2_kernel(const int* __restrict__ off,
                                                   const int* __restrict__ s_src,
                                                   const uint4* __restrict__ g,
                                                   const float* __restrict__ dinv,
                                                   float* __restrict__ t) {
  int n = blockIdx.x * 4 + (threadIdx.x >> 6);
  int lane = threadIdx.x & 63;
  int q = lane >> 3;
  int hc = lane & 7;
  int j0 = off[n], j1 = off[n + 1];
  float a[8];
#pragma unroll
  for (int i = 0; i < 8; ++i) a[i] = 0.f;
  if (q == 0) {
    uint4 v = g[(size_t)n * 8 + hc];
    a[0] = bf_lo(v.x); a[1] = bf_hi(v.x); a[2] = bf_lo(v.y); a[3] = bf_hi(v.y);
    a[4] = bf_lo(v.z); a[5] = bf_hi(v.z); a[6] = bf_lo(v.w); a[7] = bf_hi(v.w);
  }
  int j = j0 + q;
  for (; j + 8 < j1; j += 16) {
    int sa = s_src[j], sb = s_src[j + 8];
    uint4 va = g[(size_t)sa * 8 + hc];
    uint4 vb = g[(size_t)sb * 8 + hc];
    a[0] += bf_lo(va.x); a[1] += bf_hi(va.x); a[2] += bf_lo(va.y); a[3] += bf_hi(va.y);
    a[4] += bf_lo(va.z); a[5] += bf_hi(va.z); a[6] += bf_lo(va.w); a[7] += bf_hi(va.w);
    a[0] += bf_lo(vb.x); a[1] += bf_hi(vb.x); a[2] += bf_lo(vb.y); a[3] += bf_hi(vb.y);
    a[4] += bf_lo(vb.z); a[5] += bf_hi(vb.z); a[6] += bf_lo(vb.w); a[7] += bf_hi(vb.w);
  }
  if (j < j1) {
    int sa = s_src[j];
    uint4 va = g[(size_t)sa * 8 + hc];
    a[0] += bf_lo(va.x); a[1] += bf_hi(va.x); a[2] += bf_lo(va.y); a[3] += bf_hi(va.y);
    a[4] += bf_lo(va.z); a[5] += bf_hi(va.z); a[6] += bf_lo(va.w); a[7] += bf_hi(va.w);
  }
#pragma unroll
  for (int i = 0; i < 8; ++i) {
    a[i] += __shfl_xor(a[i], 8, 64);
    a[i] += __shfl_xor(a[i], 16, 64);
    a[i] += __shfl_xor(a[i], 32, 64);
  }
  if (q == 0) {
    float di = dinv[n];
    float* tp = &t[(size_t)n * HIDN + hc * 8];
    *(float4*)tp = make_float4(a[0] * di, a[1] * di, a[2] * di, a[3] * di);
    *(float4*)(tp + 4) = make_float4(a[4] * di, a[5] * di, a[6] * di, a[7] * di);
  }
}

// ---- mv: out[N,40] = t'[N,64] @ W2'[64,40] + b2 ----
// sW row z staged from W2 row perm_col(z) so the permuted t' works unchanged.
__global__ __launch_bounds__(256) void mv_kernel(const float* __restrict__ t,
                                                 const float* __restrict__ W2,
                                                 const float* __restrict__ b2,
                                                 float* __restrict__ out) {
  __shared__ float sW[HIDN * NCLS];  // 10 KB
  int tid = threadIdx.x;
  for (int i = tid; i < HIDN * (NCLS / 4); i += 256) {   // 640 float4s
    int z = i / 10, j = i - z * 10;
    int c = perm_col(z);
    ((float4*)sW)[z * 10 + j] = ((const float4*)W2)[c * 10 + j];
  }
  __syncthreads();
  int cg = tid & 1;
  int r = blockIdx.x * 128 + (tid >> 1);
  if (r >= NN) return;
  int c0 = cg * 20;
  float acc[20];
#pragma unroll
  for (int j = 0; j < 20; ++j) acc[j] = b2[c0 + j];
  const float4* t4 = (const float4*)(t + (size_t)r * HIDN);
#pragma unroll 4
  for (int k4 = 0; k4 < 16; ++k4) {
    float4 tv = t4[k4];
#pragma unroll
    for (int kk = 0; kk < 4; ++kk) {
      float xv = (&tv.x)[kk];
      const float* wr = &sW[(k4 * 4 + kk) * NCLS + c0];
#pragma unroll
      for (int j = 0; j < 5; ++j) {
        float4 wv = *(const float4*)&wr[j * 4];
        acc[j * 4 + 0] = fmaf(xv, wv.x, acc[j * 4 + 0]);
        acc[j * 4 + 1] = fmaf(xv, wv.y, acc[j * 4 + 1]);
        acc[j * 4 + 2] = fmaf(xv, wv.z, acc[j * 4 + 2]);
        acc[j * 4 + 3] = fmaf(xv, wv.w, acc[j * 4 + 3]);
      }
    }
  }
  float4* op = (float4*)&out[(size_t)r * NCLS + c0];
#pragma unroll
  for (int j = 0; j < 5; ++j)
    op[j] = make_float4(acc[j * 4 + 0], acc[j * 4 + 1],
                        acc[j * 4 + 2], acc[j * 4 + 3]);
}

extern "C" void kernel_launch(void* const* d_in, const int* in_sizes, int n_in,
                              void* d_out, int out_size, void* d_ws, size_t ws_size,
                              hipStream_t stream) {
  const float* x  = (const float*)d_in[0];
  const void*  ei = d_in[1];
  const float* W1 = (const float*)d_in[2];
  const float* b1 = (const float*)d_in[3];
  const float* W2 = (const float*)d_in[4];
  const float* b2 = (const float*)d_in[5];
  float* out = (float*)d_out;

  char* w = (char*)d_ws;
  size_t off_b = 0;
  auto carve = [&](size_t bytes) -> void* {
    void* p = w + off_b;
    off_b = (off_b + bytes + 255) & ~(size_t)255;
    return p;
  };
  int*    mat   = (int*)   carve((size_t)NEB * NBUCK * 4);   // 611 KB
  int*    tot   = (int*)   carve((size_t)NBUCK * 4);
  int*    bbase = (int*)   carve((size_t)(NBUCK + 1) * 4);
  int*    offs  = (int*)   carve((size_t)(NN + 1) * 4);
  float*  dinv  = (float*) carve((size_t)NN * 4);
  int*    flag  = (int*)   carve(256);
  int*    s_src = (int*)   carve((size_t)NE * 4);
  uint32* hs    = (uint32*)carve((size_t)NN * 32 * 4);       // bf16 h, 12.8 MB
  uint4*  g     = (uint4*) carve((size_t)NN * 8 * 16);       // bf16 g, 12.8 MB
  float*  t     = (float*) carve((size_t)NN * HIDN * 4);     // fp32, 25.6 MB
  uint32* bbuf  = (uint32*)carve((size_t)NE * 4);            // 6.4 MB
  uint4*  wfrag = (uint4*) carve((size_t)2048 * 16);         // 32 KB

  probe_kernel<<<1, 64, 0, stream>>>((const unsigned int*)ei, flag);
  wfrag_kernel<<<32, 64, 0, stream>>>(W1, wfrag);
  passA_kernel<<<NEB, 256, 0, stream>>>(ei, flag, mat);
  passB1_kernel<<<NBUCK, 512, 0, stream>>>(mat, tot);
  passB2_kernel<<<1, 512, 0, stream>>>(tot, bbase);
  passC_kernel<<<NEB, 256, 0, stream>>>(ei, flag, mat, bbase, bbuf);
  build_kernel<<<NBUCK, 256, 0, stream>>>(bbase, bbuf, offs, dinv, s_src);
  gemm1_kernel<<<(NN / 32 + 3) / 4, 256, 0, stream>>>(x, wfrag, dinv, hs);
  agg1_kernel<<<NN / 4, 256, 0, stream>>>(offs, s_src, (const uint4*)hs, dinv, b1, g);
  agg2_kernel<<<NN / 4, 256, 0, stream>>>(offs, s_src, g, dinv, t);
  mv_kernel<<<(NN + 127) / 128, 256, 0, stream>>>(t, W2, b2, out);
}

// Round 4
// 247.124 us; speedup vs baseline: 1.1641x; 1.0603x over previous
//
#include <hip/hip_runtime.h>
#include <stdint.h>

#define NN    100000
#define FIN   128
#define HIDN  64
#define NCLS  40
#define NE    1600000
#define NBUCK ((NN + 255) / 256)      // 391 buckets of 256 nodes
#define EPB   4096                    // edges per partition block
#define NEB   ((NE + EPB - 1) / EPB)  // 391 partition blocks

typedef unsigned int uint32;
typedef __attribute__((ext_vector_type(8))) short short8v;
typedef __attribute__((ext_vector_type(4))) float f32x4;

static __device__ __forceinline__ unsigned short f2bf(float f) {
  uint32 u = __float_as_uint(f);
  u = (u + 0x7fffu + ((u >> 16) & 1u)) >> 16;   // RNE
  return (unsigned short)u;
}
static __device__ __forceinline__ uint32 pack2(float lo, float hi) {
  return (uint32)f2bf(lo) | ((uint32)f2bf(hi) << 16);
}
static __device__ __forceinline__ float bf_lo(uint32 v) {
  return __uint_as_float(v << 16);
}
static __device__ __forceinline__ float bf_hi(uint32 v) {
  return __uint_as_float(v & 0xFFFF0000u);
}
static __device__ __forceinline__ f32x4 mfma_bf16(uint4 a, uint4 b, f32x4 c) {
  short8v av = __builtin_bit_cast(short8v, a);
  short8v bv = __builtin_bit_cast(short8v, b);
  return __builtin_amdgcn_mfma_f32_16x16x32_bf16(av, bv, c, 0, 0, 0);
}

// permuted hs/g/t column map: float index z in [0,64) -> true column.
// Produced by gemm1's MFMA epilogue word layout; consumed by b1/W2 remaps.
static __device__ __forceinline__ int perm_col(int z) {
  return 4 * (z >> 3) + ((z & 7) >> 1) + 16 * (z & 1) + ((z >= 32) ? 16 : 0);
}

// ---- edge dtype probe: int64 (odd u32 words all zero) vs int32 ----
__global__ __launch_bounds__(64) void probe_kernel(const unsigned int* __restrict__ raw,
                                                   int* __restrict__ flag) {
  if (threadIdx.x == 0) {
    int is64 = 1;
    for (int i = 0; i < 64; ++i)
      if (raw[2 * i + 1] != 0u) { is64 = 0; break; }
    *flag = is64;
  }
}

// ---- wfrag: W1[128][64] fp32 -> MFMA B-frag order, split hi/lo bf16 ----
// frag idx = ((t*4 + kr)*4 + nr)*64 + lane ; lane holds B[k][n] for
// n = nr*16 + (lane&15), k = kr*32 + (lane>>4)*8 + i, i=0..7 (bf16 pairs).
// Also emits b1p[z] = b1[perm_col(z)] for agg1's epilogue.
__global__ __launch_bounds__(64) void wfrag_kernel(const float* __restrict__ W,
                                                   const float* __restrict__ b1,
                                                   uint4* __restrict__ wfrag,
                                                   float* __restrict__ b1p) {
  int idx = blockIdx.x * 64 + threadIdx.x;   // 0..2047 over grid 32x64
  if (idx < 64) b1p[idx] = b1[perm_col(idx)];
  int lane = idx & 63;
  int nr = (idx >> 6) & 3;
  int kr = (idx >> 8) & 3;
  int t  = idx >> 10;                        // 0 = hi, 1 = lo
  int n  = nr * 16 + (lane & 15);
  int k0 = kr * 32 + (lane >> 4) * 8;
  uint32 w[4];
#pragma unroll
  for (int j = 0; j < 4; ++j) {
    float a = W[(k0 + 2 * j) * HIDN + n];
    float b = W[(k0 + 2 * j + 1) * HIDN + n];
    uint32 ha = f2bf(a), hb = f2bf(b);
    if (t == 0) {
      w[j] = ha | (hb << 16);
    } else {
      float ra = a - __uint_as_float(ha << 16);
      float rb = b - __uint_as_float(hb << 16);
      w[j] = (uint32)f2bf(ra) | ((uint32)f2bf(rb) << 16);
    }
  }
  wfrag[idx] = make_uint4(w[0], w[1], w[2], w[3]);
}

// ---- passA: per-block bucket histogram -> mat[blk][bucket] ----
__global__ __launch_bounds__(256) void passA_kernel(const void* __restrict__ eptr,
                                                    const int* __restrict__ flag,
                                                    int* __restrict__ mat) {
  __shared__ int cnt[NBUCK];
  int tid = threadIdx.x;
  for (int i = tid; i < NBUCK; i += 256) cnt[i] = 0;
  __syncthreads();
  int is64 = *flag;
  int base = blockIdx.x * EPB;
#pragma unroll
  for (int k = 0; k < EPB / 256; ++k) {
    int e = base + k * 256 + tid;
    if (e < NE) {
      int d = is64 ? (int)((const long long*)eptr)[e + NE]
                   : ((const int*)eptr)[e + NE];
      atomicAdd(&cnt[d >> 8], 1);
    }
  }
  __syncthreads();
  for (int i = tid; i < NBUCK; i += 256)
    mat[blockIdx.x * NBUCK + i] = cnt[i];
}

// ---- passB1: per-bucket exclusive scan over blocks; emit bucket totals ----
__global__ __launch_bounds__(512) void passB1_kernel(int* __restrict__ mat,
                                                     int* __restrict__ tot) {
  __shared__ int s[512];
  int b = blockIdx.x;         // bucket
  int t = threadIdx.x;        // block index
  int v = (t < NEB) ? mat[t * NBUCK + b] : 0;
  s[t] = v;
  __syncthreads();
#pragma unroll
  for (int d = 1; d < 512; d <<= 1) {
    int u = (t >= d) ? s[t - d] : 0;
    __syncthreads();
    s[t] += u;
    __syncthreads();
  }
  if (t < NEB) mat[t * NBUCK + b] = s[t] - v;  // exclusive prefix within bucket
  if (t == 511) tot[b] = s[511];
}

// ---- passB2: exclusive scan of bucket totals -> bbase ----
__global__ __launch_bounds__(512) void passB2_kernel(const int* __restrict__ tot,
                                                     int* __restrict__ bbase) {
  __shared__ int s[512];
  int i = threadIdx.x;
  int v = (i < NBUCK) ? tot[i] : 0;
  s[i] = v;
  __syncthreads();
#pragma unroll
  for (int d = 1; d < 512; d <<= 1) {
    int u = (i >= d) ? s[i - d] : 0;
    __syncthreads();
    s[i] += u;
    __syncthreads();
  }
  if (i < NBUCK) bbase[i] = s[i] - v;
  if (i == 511) bbase[NBUCK] = s[511];
}

// ---- passC: place edges into compact bucket-sorted bbuf (LDS cursors) ----
__global__ __launch_bounds__(256) void passC_kernel(const void* __restrict__ eptr,
                                                    const int* __restrict__ flag,
                                                    const int* __restrict__ mat,
                                                    const int* __restrict__ bbase,
                                                    uint32* __restrict__ bbuf) {
  __shared__ int cur[NBUCK];
  int tid = threadIdx.x;
  for (int i = tid; i < NBUCK; i += 256)
    cur[i] = bbase[i] + mat[blockIdx.x * NBUCK + i];
  __syncthreads();
  int is64 = *flag;
  int base = blockIdx.x * EPB;
#pragma unroll
  for (int k = 0; k < EPB / 256; ++k) {
    int e = base + k * 256 + tid;
    if (e < NE) {
      int s, d;
      if (is64) {
        const long long* p = (const long long*)eptr;
        s = (int)p[e]; d = (int)p[e + NE];
      } else {
        const int* p = (const int*)eptr;
        s = p[e]; d = p[e + NE];
      }
      int slot = atomicAdd(&cur[d >> 8], 1);
      bbuf[slot] = (uint32)s | ((uint32)(d & 255) << 17);
    }
  }
}

// ---- build: per-bucket CSR (LDS hist + scan + rank placement) ----
__global__ __launch_bounds__(256) void build_kernel(const int* __restrict__ bbase,
                                                    const uint32* __restrict__ bbuf,
                                                    int* __restrict__ off,
                                                    float* __restrict__ dinv,
                                                    int* __restrict__ s_src) {
  __shared__ int hist[256];
  __shared__ int lofs[256];
  __shared__ int rank[256];
  int b = blockIdx.x, tid = threadIdx.x;
  int base = bbase[b];
  int count = bbase[b + 1] - base;
  const uint32* p = bbuf + base;
  hist[tid] = 0;
  __syncthreads();
  for (int i = tid; i < count; i += 256) atomicAdd(&hist[p[i] >> 17], 1);
  __syncthreads();
  int deg = hist[tid];
  lofs[tid] = deg;
  __syncthreads();
#pragma unroll
  for (int dd = 1; dd < 256; dd <<= 1) {
    int t = (tid >= dd) ? lofs[tid - dd] : 0;
    __syncthreads();
    lofs[tid] += t;
    __syncthreads();
  }
  int excl = lofs[tid] - deg;
  __syncthreads();
  lofs[tid] = excl;
  rank[tid] = 0;
  int n = b * 256 + tid;
  if (n < NN) {
    off[n] = base + excl;
    dinv[n] = rsqrtf((float)deg + 1.0f);
  }
  if (b == 0 && tid == 0) off[NN] = NE;
  __syncthreads();
  for (int i = tid; i < count; i += 256) {
    uint32 v = p[i];
    int dl = (int)(v >> 17);
    int s = (int)(v & 0x1FFFFu);
    int r = atomicAdd(&rank[dl], 1);
    s_src[base + lofs[dl] + r] = s;
  }
}

// ---- GEMM1 (MFMA): hs'[N,64](bf16, perm cols) = (x @ W1) * dinv[row] ----
// R12: mfma_f32_16x16x32_bf16, split-precision (xh*wh + xh*wl + xl*wh ~ fp32).
// Per wave: 32 rows x 64 cols, 2x4 acc frags, K=128 in 4 chunks, 96 MFMAs.
// W frags read from precomputed wfrag (coalesced dwordx4, L2-hot). No LDS.
__global__ __launch_bounds__(256) void gemm1_kernel(const float* __restrict__ x,
                                                    const uint4* __restrict__ wfrag,
                                                    const float* __restrict__ dinv,
                                                    uint32* __restrict__ hs) {
  int wid = blockIdx.x * 4 + (threadIdx.x >> 6);
  if (wid >= NN / 32) return;                 // 3125 waves exactly, no LDS
  int lane = threadIdx.x & 63;
  int l15 = lane & 15, lg = lane >> 4;
  int r0 = wid * 32;
  f32x4 acc[2][4];
#pragma unroll
  for (int mr = 0; mr < 2; ++mr)
#pragma unroll
    for (int nr = 0; nr < 4; ++nr) acc[mr][nr] = (f32x4)0.f;
  const float4* x4 = (const float4*)x;
#pragma unroll
  for (int kr = 0; kr < 4; ++kr) {
    uint4 ah[2], al[2];
#pragma unroll
    for (int mr = 0; mr < 2; ++mr) {
      int m = r0 + mr * 16 + l15;
      int q0 = m * 32 + kr * 8 + lg * 2;      // float4 index of k0 = kr*32+lg*8
      float4 u = x4[q0], v = x4[q0 + 1];
      float xs[8] = {u.x, u.y, u.z, u.w, v.x, v.y, v.z, v.w};
      uint32 hw[4], lw[4];
#pragma unroll
      for (int j = 0; j < 4; ++j) {
        float a0 = xs[2 * j], a1 = xs[2 * j + 1];
        uint32 h0 = f2bf(a0), h1 = f2bf(a1);
        float ra = a0 - __uint_as_float(h0 << 16);
        float rb = a1 - __uint_as_float(h1 << 16);
        hw[j] = h0 | (h1 << 16);
        lw[j] = (uint32)f2bf(ra) | ((uint32)f2bf(rb) << 16);
      }
      ah[mr] = make_uint4(hw[0], hw[1], hw[2], hw[3]);
      al[mr] = make_uint4(lw[0], lw[1], lw[2], lw[3]);
    }
#pragma unroll
    for (int nr = 0; nr < 4; ++nr) {
      uint4 bh = wfrag[(kr * 4 + nr) * 64 + lane];          // hi set (t=0)
      uint4 bl = wfrag[((4 + kr) * 4 + nr) * 64 + lane];    // lo set (t=1)
#pragma unroll
      for (int mr = 0; mr < 2; ++mr) {
        acc[mr][nr] = mfma_bf16(ah[mr], bh, acc[mr][nr]);
        acc[mr][nr] = mfma_bf16(al[mr], bh, acc[mr][nr]);
        acc[mr][nr] = mfma_bf16(ah[mr], bl, acc[mr][nr]);
      }
    }
  }
  // epilogue: C/D frag row = 4*lg + j (within 16-tile), col = nr*16 + l15
#pragma unroll
  for (int mr = 0; mr < 2; ++mr) {
    int rb = r0 + mr * 16 + 4 * lg;
    float4 dv = *(const float4*)&dinv[rb];
#pragma unroll
    for (int a = 0; a < 2; ++a) {
#pragma unroll
      for (int j = 0; j < 4; ++j) {
        float d = (&dv.x)[j];
        uint32 wv = pack2(acc[mr][2 * a][j] * d, acc[mr][2 * a + 1][j] * d);
        hs[(size_t)(rb + j) * 32 + a * 16 + l15] = wv;
      }
    }
  }
}

// ---- agg1 (R13 reshape): wave = 8 nodes x 8 col-lanes; each lane owns 8
// cols of one node, loops its edge list serially (unroll x2 => 2 gathers in
// flight). Zero shuffles; per-node fixed cost amortized 8x across lanes.
// g[n] = bf16(dinv_n*relu(dinv_n*(hs[n]+sum)+b1)) ----
__global__ __launch_bounds__(256) void agg1_kernel(const int* __restrict__ off,
                                                   const int* __restrict__ s_src,
                                                   const uint4* __restrict__ hs4,
                                                   const float* __restrict__ dinv,
                                                   const float* __restrict__ b1p,
                                                   uint4* __restrict__ g) {
  int tid = threadIdx.x;
  int n = blockIdx.x * 32 + (tid >> 3);   // 32 nodes/block, 3125 blocks exact
  int hc = tid & 7;                       // 16B chunk (8 cols) this lane owns
  int j0 = off[n], j1 = off[n + 1];
  float a[8];
  {
    uint4 v = hs4[(size_t)n * 8 + hc];    // self term
    a[0] = bf_lo(v.x); a[1] = bf_hi(v.x); a[2] = bf_lo(v.y); a[3] = bf_hi(v.y);
    a[4] = bf_lo(v.z); a[5] = bf_hi(v.z); a[6] = bf_lo(v.w); a[7] = bf_hi(v.w);
  }
  int j = j0;
  for (; j + 1 < j1; j += 2) {
    int sa = s_src[j], sb = s_src[j + 1];
    uint4 va = hs4[(size_t)sa * 8 + hc];
    uint4 vb = hs4[(size_t)sb * 8 + hc];
    a[0] += bf_lo(va.x); a[1] += bf_hi(va.x); a[2] += bf_lo(va.y); a[3] += bf_hi(va.y);
    a[4] += bf_lo(va.z); a[5] += bf_hi(va.z); a[6] += bf_lo(va.w); a[7] += bf_hi(va.w);
    a[0] += bf_lo(vb.x); a[1] += bf_hi(vb.x); a[2] += bf_lo(vb.y); a[3] += bf_hi(vb.y);
    a[4] += bf_lo(vb.z); a[5] += bf_hi(vb.z); a[6] += bf_lo(vb.w); a[7] += bf_hi(vb.w);
  }
  if (j < j1) {
    int sa = s_src[j];
    uint4 va = hs4[(size_t)sa * 8 + hc];
    a[0] += bf_lo(va.x); a[1] += bf_hi(va.x); a[2] += bf_lo(va.y); a[3] += bf_hi(va.y);
    a[4] += bf_lo(va.z); a[5] += bf_hi(va.z); a[6] += bf_lo(va.w); a[7] += bf_hi(va.w);
  }
  float di = dinv[n];
  float4 b0 = *(const float4*)&b1p[hc * 8];
  float4 b4 = *(const float4*)&b1p[hc * 8 + 4];
  float r0 = di * fmaxf(a[0] * di + b0.x, 0.f);
  float r1 = di * fmaxf(a[1] * di + b0.y, 0.f);
  float r2 = di * fmaxf(a[2] * di + b0.z, 0.f);
  float r3 = di * fmaxf(a[3] * di + b0.w, 0.f);
  float r4 = di * fmaxf(a[4] * di + b4.x, 0.f);
  float r5 = di * fmaxf(a[5] * di + b4.y, 0.f);
  float r6 = di * fmaxf(a[6] * di + b4.z, 0.f);
  float r7 = di * fmaxf(a[7] * di + b4.w, 0.f);
  uint4 o;
  o.x = pack2(r0, r1); o.y = pack2(r2, r3);
  o.z = pack2(r4, r5); o.w = pack2(r6, r7);
  g[(size_t)n * 8 + hc] = o;     // 8 lanes x 16B = 128B contiguous per node
}

// ---- agg2 (R13 reshape, same shape on g); t[n] = dinv_n*(g[n]+sum) fp32 ----
__global__ __launch_bounds__(256) void agg2_kernel(const int* __restrict__ off,
                                                   const int* __restrict__ s_src,
                                                   const uint4* __restrict__ g,
                                                   const float* __restrict__ dinv,
                                                   float* __restrict__ t) {
  int tid = threadIdx.x;
  int n = blockIdx.x * 32 + (tid >> 3);
  int hc = tid & 7;
  int j0 = off[n], j1 = off[n + 1];
  float a[8];
  {
    uint4 v = g[(size_t)n * 8 + hc];      // self term
    a[0] = bf_lo(v.x); a[1] = bf_hi(v.x); a[2] = bf_lo(v.y); a[3] = bf_hi(v.y);
    a[4] = bf_lo(v.z); a[5] = bf_hi(v.z); a[6] = bf_lo(v.w); a[7] = bf_hi(v.w);
  }
  int j = j0;
  for (; j + 1 < j1; j += 2) {
    int sa = s_src[j], sb = s_src[j + 1];
    uint4 va = g[(size_t)sa * 8 + hc];
    uint4 vb = g[(size_t)sb * 8 + hc];
    a[0] += bf_lo(va.x); a[1] += bf_hi(va.x); a[2] += bf_lo(va.y); a[3] += bf_hi(va.y);
    a[4] += bf_lo(va.z); a[5] += bf_hi(va.z); a[6] += bf_lo(va.w); a[7] += bf_hi(va.w);
    a[0] += bf_lo(vb.x); a[1] += bf_hi(vb.x); a[2] += bf_lo(vb.y); a[3] += bf_hi(vb.y);
    a[4] += bf_lo(vb.z); a[5] += bf_hi(vb.z); a[6] += bf_lo(vb.w); a[7] += bf_hi(vb.w);
  }
  if (j < j1) {
    int sa = s_src[j];
    uint4 va = g[(size_t)sa * 8 + hc];
    a[0] += bf_lo(va.x); a[1] += bf_hi(va.x); a[2] += bf_lo(va.y); a[3] += bf_hi(va.y);
    a[4] += bf_lo(va.z); a[5] += bf_hi(va.z); a[6] += bf_lo(va.w); a[7] += bf_hi(va.w);
  }
  float di = dinv[n];
  float* tp = &t[(size_t)n * HIDN + hc * 8];
  *(float4*)tp = make_float4(a[0] * di, a[1] * di, a[2] * di, a[3] * di);
  *(float4*)(tp + 4) = make_float4(a[4] * di, a[5] * di, a[6] * di, a[7] * di);
}

// ---- mv: out[N,40] = t'[N,64] @ W2'[64,40] + b2 ----
// sW row z staged from W2 row perm_col(z) so the permuted t' works unchanged.
__global__ __launch_bounds__(256) void mv_kernel(const float* __restrict__ t,
                                                 const float* __restrict__ W2,
                                                 const float* __restrict__ b2,
                                                 float* __restrict__ out) {
  __shared__ float sW[HIDN * NCLS];  // 10 KB
  int tid = threadIdx.x;
  for (int i = tid; i < HIDN * (NCLS / 4); i += 256) {   // 640 float4s
    int z = i / 10, j = i - z * 10;
    int c = perm_col(z);
    ((float4*)sW)[z * 10 + j] = ((const float4*)W2)[c * 10 + j];
  }
  __syncthreads();
  int cg = tid & 1;
  int r = blockIdx.x * 128 + (tid >> 1);
  if (r >= NN) return;
  int c0 = cg * 20;
  float acc[20];
#pragma unroll
  for (int j = 0; j < 20; ++j) acc[j] = b2[c0 + j];
  const float4* t4 = (const float4*)(t + (size_t)r * HIDN);
#pragma unroll 4
  for (int k4 = 0; k4 < 16; ++k4) {
    float4 tv = t4[k4];
#pragma unroll
    for (int kk = 0; kk < 4; ++kk) {
      float xv = (&tv.x)[kk];
      const float* wr = &sW[(k4 * 4 + kk) * NCLS + c0];
#pragma unroll
      for (int j = 0; j < 5; ++j) {
        float4 wv = *(const float4*)&wr[j * 4];
        acc[j * 4 + 0] = fmaf(xv, wv.x, acc[j * 4 + 0]);
        acc[j * 4 + 1] = fmaf(xv, wv.y, acc[j * 4 + 1]);
        acc[j * 4 + 2] = fmaf(xv, wv.z, acc[j * 4 + 2]);
        acc[j * 4 + 3] = fmaf(xv, wv.w, acc[j * 4 + 3]);
      }
    }
  }
  float4* op = (float4*)&out[(size_t)r * NCLS + c0];
#pragma unroll
  for (int j = 0; j < 5; ++j)
    op[j] = make_float4(acc[j * 4 + 0], acc[j * 4 + 1],
                        acc[j * 4 + 2], acc[j * 4 + 3]);
}

extern "C" void kernel_launch(void* const* d_in, const int* in_sizes, int n_in,
                              void* d_out, int out_size, void* d_ws, size_t ws_size,
                              hipStream_t stream) {
  const float* x  = (const float*)d_in[0];
  const void*  ei = d_in[1];
  const float* W1 = (const float*)d_in[2];
  const float* b1 = (const float*)d_in[3];
  const float* W2 = (const float*)d_in[4];
  const float* b2 = (const float*)d_in[5];
  float* out = (float*)d_out;

  char* w = (char*)d_ws;
  size_t off_b = 0;
  auto carve = [&](size_t bytes) -> void* {
    void* p = w + off_b;
    off_b = (off_b + bytes + 255) & ~(size_t)255;
    return p;
  };
  int*    mat   = (int*)   carve((size_t)NEB * NBUCK * 4);   // 611 KB
  int*    tot   = (int*)   carve((size_t)NBUCK * 4);
  int*    bbase = (int*)   carve((size_t)(NBUCK + 1) * 4);
  int*    offs  = (int*)   carve((size_t)(NN + 1) * 4);
  float*  dinv  = (float*) carve((size_t)NN * 4);
  int*    flag  = (int*)   carve(256);
  int*    s_src = (int*)   carve((size_t)NE * 4);
  uint32* hs    = (uint32*)carve((size_t)NN * 32 * 4);       // bf16 h, 12.8 MB
  uint4*  g     = (uint4*) carve((size_t)NN * 8 * 16);       // bf16 g, 12.8 MB
  float*  t     = (float*) carve((size_t)NN * HIDN * 4);     // fp32, 25.6 MB
  uint32* bbuf  = (uint32*)carve((size_t)NE * 4);            // 6.4 MB
  uint4*  wfrag = (uint4*) carve((size_t)2048 * 16);         // 32 KB
  float*  b1p   = (float*) carve((size_t)HIDN * 4);          // 256 B

  probe_kernel<<<1, 64, 0, stream>>>((const unsigned int*)ei, flag);
  wfrag_kernel<<<32, 64, 0, stream>>>(W1, b1, wfrag, b1p);
  passA_kernel<<<NEB, 256, 0, stream>>>(ei, flag, mat);
  passB1_kernel<<<NBUCK, 512, 0, stream>>>(mat, tot);
  passB2_kernel<<<1, 512, 0, stream>>>(tot, bbase);
  passC_kernel<<<NEB, 256, 0, stream>>>(ei, flag, mat, bbase, bbuf);
  build_kernel<<<NBUCK, 256, 0, stream>>>(bbase, bbuf, offs, dinv, s_src);
  gemm1_kernel<<<(NN / 32 + 3) / 4, 256, 0, stream>>>(x, wfrag, dinv, hs);
  agg1_kernel<<<NN / 32, 256, 0, stream>>>(offs, s_src, (const uint4*)hs, dinv, b1p, g);
  agg2_kernel<<<NN / 32, 256, 0, stream>>>(offs, s_src, g, dinv, t);
  mv_kernel<<<(NN + 127) / 128, 256, 0, stream>>>(t, W2, b2, out);
}